// Round 5
// baseline (361.126 us; speedup 1.0000x reference)
//
#include <hip/hip_runtime.h>
#include <hip/hip_bf16.h>
#include <stdint.h>

// Problem constants (fixed by setup_inputs)
constexpr int Bn  = 8;
constexpr int Cc  = 512;
constexpr int ICc = 256;
constexpr int HWc = 48 * 48;           // 2304
constexpr float BN_EPS = 1e-5f;

typedef unsigned short u16;
typedef __attribute__((ext_vector_type(8))) short short8;   // 8 bf16 (4 VGPRs)
typedef __attribute__((ext_vector_type(4))) float f32x4;    // MFMA C/D frag

__device__ __forceinline__ u16 f2bf(float f) {
    uint32_t u = __builtin_bit_cast(uint32_t, f);
    u += 0x7fffu + ((u >> 16) & 1u);     // RNE
    return (u16)(u >> 16);
}
// async global->LDS, 16B per lane; lds dst is wave-uniform base (HW adds lane*16)
__device__ __forceinline__ void load_lds16(const void* g, void* l) {
    __builtin_amdgcn_global_load_lds(
        (const __attribute__((address_space(1))) void*)(uintptr_t)g,
        (__attribute__((address_space(3))) void*)(uintptr_t)l, 16, 0, 0);
}

// ---------------------------------------------------------------------------
// Front cast: thph_w bf16 (rows 0..255=th_w, 256..511=ph_w), g_w bf16,
// bias_thph fp32 [th_b | ph_b].
// ---------------------------------------------------------------------------
__global__ __launch_bounds__(256)
void cast_front(const float* __restrict__ th_w, const float* __restrict__ ph_w,
                const float* __restrict__ g_w, const float* __restrict__ th_b,
                const float* __restrict__ ph_b, u16* __restrict__ wcat,
                float* __restrict__ bias_thph) {
    int idx = blockIdx.x * 256 + threadIdx.x;
    if (idx < 98304) {                           // ushort4 casts
        const float4* src;
        if (idx < 32768)       src = (const float4*)th_w + idx;
        else if (idx < 65536)  src = (const float4*)ph_w + (idx - 32768);
        else                   src = (const float4*)g_w  + (idx - 65536);
        float4 v = *src;
        ushort4 o;
        o.x = f2bf(v.x); o.y = f2bf(v.y); o.z = f2bf(v.z); o.w = f2bf(v.w);
        ((ushort4*)wcat)[idx] = o;
    } else if (idx < 98816) {                    // 512 bias floats
        int i = idx - 98304;
        bias_thph[i] = (i < 256) ? th_b[i] : ph_b[i - 256];
    }
}

__global__ __launch_bounds__(256)
void cast_w(const float* __restrict__ a, u16* __restrict__ out) {
    int idx = blockIdx.x * 256 + threadIdx.x;    // 0..32767
    float4 v = ((const float4*)a)[idx];
    ushort4 o;
    o.x = f2bf(v.x); o.y = f2bf(v.y); o.z = f2bf(v.z); o.w = f2bf(v.w);
    ((ushort4*)out)[idx] = o;
}

// ---------------------------------------------------------------------------
// x (B,C,HW) fp32 -> xt (B,HW,C) bf16, 64c x 32p LDS-tiled, ushort2 stores
// ---------------------------------------------------------------------------
__global__ __launch_bounds__(256)
void transpose_cast_x(const float* __restrict__ x, u16* __restrict__ xt) {
    __shared__ float t[64][33];
    const int b = blockIdx.z;
    const int p0 = blockIdx.x * 32;     // HW dir
    const int c0 = blockIdx.y * 64;     // C dir
    const int tx = threadIdx.x & 31, ty = threadIdx.x >> 5;   // ty 0..7
    const float* xb = x + (size_t)b * Cc * HWc;
#pragma unroll
    for (int r = 0; r < 8; ++r)
        t[r * 8 + ty][tx] = xb[(size_t)(c0 + r * 8 + ty) * HWc + p0 + tx];
    __syncthreads();
    u16* xtb = xt + (size_t)b * HWc * Cc;
    const int cc = (threadIdx.x & 31) * 2, pp = threadIdx.x >> 5;
#pragma unroll
    for (int r = 0; r < 4; ++r) {
        int p = r * 8 + pp;
        ushort2 v;
        v.x = f2bf(t[cc][p]);
        v.y = f2bf(t[cc + 1][p]);
        *(ushort2*)&xtb[(size_t)(p0 + p) * Cc + c0 + cc] = v;
    }
}

// ---------------------------------------------------------------------------
// bf16 MFMA GEMM: C[m][n] = sum_k A[m][k] * B[n][k] (+ bias)
// TM=128 or 64; STORE 0=bf16, 1=fp32; STATS: fused BN sum/sumsq per m.
// ---------------------------------------------------------------------------
template <int TM, int STORE, bool STATS>
__global__ __launch_bounds__(256, 2)
void mfma_gemm(const u16* __restrict__ A, const u16* __restrict__ B,
               void* __restrict__ Cout, const float* __restrict__ bias,
               int bias_mode, int K, int ldA, int ldB, int ldC,
               size_t sA, size_t sB, size_t sC,
               float* __restrict__ s0g, float* __restrict__ s1g) {
    constexpr int MI = TM / 32;                  // 4 (TM=128) or 2 (TM=64)
    __shared__ __align__(16) u16 As[TM * 32];
    __shared__ __align__(16) u16 Bs[128 * 32];
    const int bz = blockIdx.z;
    const int m0 = blockIdx.y * TM, n0 = blockIdx.x * 128;
    const u16* Ab = A + (size_t)bz * sA + (size_t)m0 * ldA;
    const u16* Bb = B + (size_t)bz * sB + (size_t)n0 * ldB;
    const int tid = threadIdx.x, lane = tid & 63, w = tid >> 6;
    const int wm = (w & 1) * (TM / 2);
    const int wn = (w >> 1) * 64;
    const int quad = lane >> 4, m16 = lane & 15;

    f32x4 acc[MI][4];
#pragma unroll
    for (int i = 0; i < MI; ++i)
#pragma unroll
        for (int j = 0; j < 4; ++j) acc[i][j] = (f32x4){0.f, 0.f, 0.f, 0.f};

    const int L0 = 2 * w * 64 + lane, L1 = L0 + 64;
    const int br0 = L0 >> 2, bc0 = (L0 & 3) * 8;
    const int br1 = L1 >> 2, bc1 = (L1 & 3) * 8;
    const int ar0 = (TM == 128) ? br0 : (tid >> 2);
    const int ac0 = (TM == 128) ? bc0 : (tid & 3) * 8;

    for (int k0 = 0; k0 < K; k0 += 32) {
        if (TM == 128) {
            load_lds16(Ab + (size_t)ar0 * ldA + k0 + ac0, &As[2 * w * 512]);
            load_lds16(Ab + (size_t)br1 * ldA + k0 + bc1, &As[(2 * w + 1) * 512]);
        } else {
            load_lds16(Ab + (size_t)ar0 * ldA + k0 + ac0, &As[w * 512]);
        }
        load_lds16(Bb + (size_t)br0 * ldB + k0 + bc0, &Bs[2 * w * 512]);
        load_lds16(Bb + (size_t)br1 * ldB + k0 + bc1, &Bs[(2 * w + 1) * 512]);
        __syncthreads();

        short8 af[MI], bfv[4];
#pragma unroll
        for (int i = 0; i < MI; ++i)
            af[i] = *(const short8*)&As[(wm + i * 16 + m16) * 32 + quad * 8];
#pragma unroll
        for (int j = 0; j < 4; ++j)
            bfv[j] = *(const short8*)&Bs[(wn + j * 16 + m16) * 32 + quad * 8];
#pragma unroll
        for (int i = 0; i < MI; ++i)
#pragma unroll
            for (int j = 0; j < 4; ++j)
                acc[i][j] = __builtin_amdgcn_mfma_f32_16x16x32_bf16(
                    af[i], bfv[j], acc[i][j], 0, 0, 0);
        __syncthreads();
    }

    if (bias_mode) {
#pragma unroll
        for (int i = 0; i < MI; ++i)
#pragma unroll
            for (int j = 0; j < 4; ++j)
#pragma unroll
                for (int r = 0; r < 4; ++r)
                    acc[i][j][r] += (bias_mode == 2)
                        ? bias[m0 + wm + i * 16 + quad * 4 + r]
                        : bias[n0 + wn + j * 16 + m16];
    }

    if (STORE == 0) {
        u16* C = (u16*)Cout + (size_t)bz * sC;
#pragma unroll
        for (int i = 0; i < MI; ++i) {
            int m = m0 + wm + i * 16 + quad * 4;
#pragma unroll
            for (int j = 0; j < 4; ++j) {
                int n = n0 + wn + j * 16 + m16;
#pragma unroll
                for (int r = 0; r < 4; ++r)
                    C[(size_t)(m + r) * ldC + n] = f2bf(acc[i][j][r]);
            }
        }
    } else {
        float* C = (float*)Cout + (size_t)bz * sC;
#pragma unroll
        for (int i = 0; i < MI; ++i) {
            int m = m0 + wm + i * 16 + quad * 4;
#pragma unroll
            for (int j = 0; j < 4; ++j) {
                int n = n0 + wn + j * 16 + m16;
#pragma unroll
                for (int r = 0; r < 4; ++r)
                    C[(size_t)(m + r) * ldC + n] = acc[i][j][r];
            }
        }
    }

    if (STATS) {
#pragma unroll
        for (int i = 0; i < MI; ++i) {
#pragma unroll
            for (int r = 0; r < 4; ++r) {
                float v0 = 0.f, v1 = 0.f;
#pragma unroll
                for (int j = 0; j < 4; ++j) {
                    float v = acc[i][j][r];
                    v0 += v;
                    v1 = fmaf(v, v, v1);
                }
#pragma unroll
                for (int off = 8; off; off >>= 1) {
                    v0 += __shfl_down(v0, off, 16);
                    v1 += __shfl_down(v1, off, 16);
                }
                if (m16 == 0) {
                    int m = m0 + wm + i * 16 + quad * 4 + r;
                    atomicAdd(&s0g[m], v0);
                    atomicAdd(&s1g[m], v1);
                }
            }
        }
    }
}

// ---------------------------------------------------------------------------
// Fused flash attention: y = softmax(theta . phi^T) . g^T, never storing S.
//   thph: (B, HW, 512) bf16 — theta cols 0..255, phi cols 256..511
//   g   : (B, IC, HW)  bf16 (V in B-operand layout: rows ic, k = key)
//   y   : (B, HW, IC)  bf16
// Block: 64 queries, 4 waves (16 q each). Loop 18 key-tiles of 128.
// LDS (u16 offsets): Ks0 0, Ks1 4096, Vs 8192 (8192), Ps 16384 (4x2176);
// Q tile staged once at 8192 (dead after q-frags load).
// ---------------------------------------------------------------------------
__global__ __launch_bounds__(256, 2)
void flash_attn(const u16* __restrict__ thph, const u16* __restrict__ g,
                u16* __restrict__ y) {
    __shared__ __align__(16) u16 smem[25088];    // 50,176 B -> 2 blocks/CU
    const int bz = blockIdx.y;
    const int q0 = blockIdx.x * 64;
    const u16* Qb = thph + (size_t)bz * HWc * 512 + (size_t)q0 * 512;
    const u16* Kb = thph + (size_t)bz * HWc * 512 + 256;
    const u16* Vb = g + (size_t)bz * ICc * HWc;
    const int tid = threadIdx.x, lane = tid & 63, w = tid >> 6;
    const int quad = lane >> 4, m16 = lane & 15;
    const int wm = w * 16;

    // ---- stage Q tile (64 x 256) at smem+8192, load A-frags ----
#pragma unroll
    for (int t = 0; t < 8; ++t) {
        int L = (w * 8 + t) * 64 + lane;             // 2048 slots
        int row = L >> 5, col = (L & 31) * 8;
        load_lds16(Qb + (size_t)row * 512 + col, &smem[8192 + (w * 8 + t) * 512]);
    }
    __syncthreads();
    short8 qf[8];
#pragma unroll
    for (int c = 0; c < 8; ++c)
        qf[c] = *(const short8*)&smem[8192 + (wm + m16) * 256 + c * 32 + quad * 8];
    __syncthreads();                                  // Q region now dead

    f32x4 O[16];
#pragma unroll
    for (int i = 0; i < 16; ++i) O[i] = (f32x4){0.f, 0.f, 0.f, 0.f};
    float mrow[4] = {-1e30f, -1e30f, -1e30f, -1e30f};
    float lrow[4] = {0.f, 0.f, 0.f, 0.f};

    for (int kt = 0; kt < 18; ++kt) {
        const u16* Kt = Kb + (size_t)kt * 128 * 512;
        f32x4 Sa[8];
#pragma unroll
        for (int j = 0; j < 8; ++j) Sa[j] = (f32x4){0.f, 0.f, 0.f, 0.f};

        // ---- S tile: Q (64x256) . K^T (128 keys), dims in chunks of 2x32 ----
#pragma unroll
        for (int kc = 0; kc < 4; ++kc) {
#pragma unroll
            for (int h = 0; h < 2; ++h) {
                int cdim = (kc * 2 + h) * 32;
#pragma unroll
                for (int t = 0; t < 2; ++t) {
                    int L = (w * 2 + t) * 64 + lane;  // 512 slots: 128 keys x 4
                    int row = L >> 2, col = (L & 3) * 8;
                    load_lds16(Kt + (size_t)row * 512 + cdim + col,
                               &smem[h * 4096 + (w * 2 + t) * 512]);
                }
            }
            __syncthreads();
#pragma unroll
            for (int h = 0; h < 2; ++h)
#pragma unroll
                for (int j = 0; j < 8; ++j) {
                    short8 kf = *(const short8*)
                        &smem[h * 4096 + (j * 16 + m16) * 32 + quad * 8];
                    Sa[j] = __builtin_amdgcn_mfma_f32_16x16x32_bf16(
                        qf[kc * 2 + h], kf, Sa[j], 0, 0, 0);
                }
            __syncthreads();
        }

        // ---- online softmax (C layout: col key = m16 + 16j, row q = quad*4+r)
        float alpha[4];
#pragma unroll
        for (int r = 0; r < 4; ++r) {
            float tm = Sa[0][r];
#pragma unroll
            for (int j = 1; j < 8; ++j) tm = fmaxf(tm, Sa[j][r]);
#pragma unroll
            for (int off = 1; off < 16; off <<= 1)
                tm = fmaxf(tm, __shfl_xor(tm, off, 16));
            float nm = fmaxf(mrow[r], tm);
            alpha[r] = __expf(mrow[r] - nm);
            mrow[r] = nm;
            float ps = 0.f;
#pragma unroll
            for (int j = 0; j < 8; ++j) {
                float p = __expf(Sa[j][r] - nm);
                Sa[j][r] = p;
                ps += p;
            }
#pragma unroll
            for (int off = 1; off < 16; off <<= 1)
                ps += __shfl_xor(ps, off, 16);
            lrow[r] = lrow[r] * alpha[r] + ps;
        }
#pragma unroll
        for (int j2 = 0; j2 < 16; ++j2)
#pragma unroll
            for (int r = 0; r < 4; ++r) O[j2][r] *= alpha[r];

        // ---- P: C-layout -> A-layout via per-wave private LDS (no barrier) --
        u16* Pw = &smem[16384 + w * 2176];            // 16 q x 136 (pad->16B align)
#pragma unroll
        for (int j = 0; j < 8; ++j)
#pragma unroll
            for (int r = 0; r < 4; ++r)
                Pw[(quad * 4 + r) * 136 + j * 16 + m16] = f2bf(Sa[j][r]);
        short8 pf[4];
#pragma unroll
        for (int c2 = 0; c2 < 4; ++c2)
            pf[c2] = *(const short8*)&Pw[m16 * 136 + c2 * 32 + quad * 8];

        // ---- O += P (64x128) . V^T; V staged 256 ic x 32 keys per chunk ----
#pragma unroll
        for (int c2 = 0; c2 < 4; ++c2) {
            int keyc = kt * 128 + c2 * 32;
#pragma unroll
            for (int t = 0; t < 4; ++t) {
                int L = (w * 4 + t) * 64 + lane;      // 1024 slots: 256 ic x 4
                int row = L >> 2, col = (L & 3) * 8;
                load_lds16(Vb + (size_t)row * HWc + keyc + col,
                           &smem[8192 + (w * 4 + t) * 512]);
            }
            __syncthreads();
#pragma unroll
            for (int j2 = 0; j2 < 16; ++j2) {
                short8 vf = *(const short8*)
                    &smem[8192 + (j2 * 16 + m16) * 32 + quad * 8];
                O[j2] = __builtin_amdgcn_mfma_f32_16x16x32_bf16(
                    pf[c2], vf, O[j2], 0, 0, 0);
            }
            __syncthreads();
        }
    }

    // ---- epilogue: normalize, store y (B,HW,IC) ----
    float rinv[4];
#pragma unroll
    for (int r = 0; r < 4; ++r) rinv[r] = 1.0f / lrow[r];
    u16* yb = y + ((size_t)bz * HWc + q0 + wm) * ICc;
#pragma unroll
    for (int j2 = 0; j2 < 16; ++j2)
#pragma unroll
        for (int r = 0; r < 4; ++r)
            yb[(size_t)(quad * 4 + r) * ICc + j2 * 16 + m16] =
                f2bf(O[j2][r] * rinv[r]);
}

// ---------------------------------------------------------------------------
// Normalize (from raw sums) + affine + residual, float4 vectorized
// ---------------------------------------------------------------------------
__global__ __launch_bounds__(256)
void bn_apply(const float* __restrict__ wy, const float* __restrict__ x,
              const float* __restrict__ s0, const float* __restrict__ s1,
              const float* __restrict__ gamma, const float* __restrict__ beta,
              float* __restrict__ out) {
    const size_t i4 = (size_t)blockIdx.x * 256 + threadIdx.x;
    const size_t base = i4 * 4;
    const int o = (int)((base / HWc) % Cc);
    const float N = (float)(Bn * HWc);
    const float mean = s0[o] / N;
    const float var  = s1[o] / N - mean * mean;
    const float rstd = rsqrtf(var + BN_EPS);
    const float ga = gamma[o];
    const float be = beta[o];
    const float4 w4 = ((const float4*)wy)[i4];
    const float4 x4 = ((const float4*)x)[i4];
    float4 r;
    r.x = (w4.x - mean) * rstd * ga + be + x4.x;
    r.y = (w4.y - mean) * rstd * ga + be + x4.y;
    r.z = (w4.z - mean) * rstd * ga + be + x4.z;
    r.w = (w4.w - mean) * rstd * ga + be + x4.w;
    ((float4*)out)[i4] = r;
}

// ---------------------------------------------------------------------------
extern "C" void kernel_launch(void* const* d_in, const int* in_sizes, int n_in,
                              void* d_out, int out_size, void* d_ws, size_t ws_size,
                              hipStream_t stream) {
    const float* x     = (const float*)d_in[0];
    const float* g_w   = (const float*)d_in[1];
    const float* g_b   = (const float*)d_in[2];
    const float* th_w  = (const float*)d_in[3];
    const float* th_b  = (const float*)d_in[4];
    const float* ph_w  = (const float*)d_in[5];
    const float* ph_b  = (const float*)d_in[6];
    const float* w_w   = (const float*)d_in[7];
    const float* w_b   = (const float*)d_in[8];
    const float* gamma = (const float*)d_in[9];
    const float* beta  = (const float*)d_in[10];

    // Workspace (no S materialization anymore): 95.4 MB total
    char* base = (char*)d_ws;
    u16* thph = (u16*)base;                               // 18,874,368 B
    u16* g    = (u16*)(base + 18874368);                  //  9,437,184 B
    u16* xt   = (u16*)(base + 28311552);                  // 18,874,368 B
    u16* wcat = (u16*)(base + 47185920);                  //    786,432 B
    float* bias_thph = (float*)(base + 47972352);         //      2,048 B
    u16* wbf2 = (u16*)(base + 47974400);                  //    262,144 B
    float* stats = (float*)(base + 48236544);             //      4,096 B
    u16* y    = (u16*)(base + 48240640);                  //  9,437,184 B
    float* wy = (float*)(base + 57677824);                // 37,748,736 B

    dim3 blk(256);
    const u16* thphw = wcat;                   // (512,512)
    const u16* gwb   = wcat + 262144;          // (256,512)

    cast_front<<<dim3(386), blk, 0, stream>>>(th_w, ph_w, g_w, th_b, ph_b,
                                              wcat, bias_thph);
    cast_w<<<dim3(128), blk, 0, stream>>>(w_w, wbf2);
    hipMemsetAsync(stats, 0, 2 * Cc * sizeof(float), stream);
    transpose_cast_x<<<dim3(HWc / 32, Cc / 64, Bn), blk, 0, stream>>>(x, xt);

    // thph[q][o] = sum_c xt[q][c]*thph_w[o][c] + bias  (M=2304,N=512,K=512)
    mfma_gemm<128, 0, false><<<dim3(4, 18, Bn), blk, 0, stream>>>(
        xt, thphw, thph, bias_thph, 1, Cc, Cc, Cc, 512,
        (size_t)HWc * Cc, 0, (size_t)HWc * 512, nullptr, nullptr);

    // g[ic][p] = sum_c g_w[ic][c]*xt[p][c] + g_b[ic]   (M=256,N=2304,K=512)
    mfma_gemm<64, 0, false><<<dim3(18, 4, Bn), blk, 0, stream>>>(
        gwb, xt, g, g_b, 2, Cc, Cc, Cc, HWc,
        0, (size_t)HWc * Cc, (size_t)ICc * HWc, nullptr, nullptr);

    // fused attention: y = softmax(theta.phi^T).g^T  (no S in HBM)
    flash_attn<<<dim3(HWc / 64, Bn), blk, 0, stream>>>(thph, g, y);

    // wy[o][p] = sum_ic w_w[o][ic]*y[p][ic] + w_b[o]  (M=512,N=2304,K=256)
    // fp32 out + fused BN sum/sumsq
    mfma_gemm<128, 1, true><<<dim3(18, 4, Bn), blk, 0, stream>>>(
        wbf2, y, wy, w_b, 2, ICc, ICc, ICc, HWc,
        0, (size_t)HWc * ICc, (size_t)Cc * HWc, stats, stats + Cc);

    // BatchNorm apply (stats from raw sums) + affine + residual
    bn_apply<<<dim3((Bn * Cc * HWc) / 4 / 256), blk, 0, stream>>>(
        wy, x, stats, stats + Cc, gamma, beta, (float*)d_out);
}